// Round 12
// baseline (295.327 us; speedup 1.0000x reference)
//
#include <hip/hip_runtime.h>

typedef __bf16 bf16x8 __attribute__((ext_vector_type(8)));
typedef __bf16 bf16x4 __attribute__((ext_vector_type(4)));
typedef float  f32x4  __attribute__((ext_vector_type(4)));
typedef float  f32x2  __attribute__((ext_vector_type(2)));

constexpr int OBS   = 20;
constexpr int PRED  = 12;
constexpr int SLST  = 136;            // slab row stride in bf16 (272 B, padded: 68 dwords -> 4m bank walk)
constexpr int RPB   = 256;            // rows per block (16 waves x 16 rows)
constexpr int GRID  = 256;            // 65536 / 256 -> 1 block per CU

// gate pre-scales folded into weights/biases:
// i,f,o scaled by -log2(e)  -> sigmoid(x) = rcp(1 + exp2(gate))
// g     scaled by +2*log2(e)-> tanh(x)    = (exp2(gate)-1)/(exp2(gate)+1)
constexpr float SIO = -1.4426950408889634f;
constexpr float SG  =  2.8853900817779268f;

// LDS layout (dynamic). W frags first (16B aligned), then slab, then smalls.
constexpr int OFF_W     = 0;                  // bf16x8[4096] = 64 KiB  (frag f = (c*4+ug)*4+kt, entry f*64+lane)
constexpr int OFF_SLAB  = 65536;              // bf16[256*136] = 69632 B (cols 0..63 = x, 64..127 = h)
constexpr int OFF_EMBC  = OFF_SLAB + 69632;   // float4[64]  (135168 % 16 == 0)
constexpr int OFF_BIASE = OFF_EMBC + 1024;    // float[256] fragment-ordered [(ug*4+c)*16 + q*4 + r]
constexpr int OFF_BIASD = OFF_BIASE + 1024;   // float[256]
constexpr int OFF_WFC   = OFF_BIASD + 1024;   // float[128]
constexpr int OFF_BFC   = OFF_WFC + 512;      // float[2]
constexpr int LDS_BYTES = OFF_BFC + 16;       // 138768

__device__ __forceinline__ float exp2_(float x) { return __builtin_amdgcn_exp2f(x); }
__device__ __forceinline__ float rcp_(float x)  { return __builtin_amdgcn_rcpf(x); }

// Row-split wave-autonomous LSTM: each wave owns 16 batch rows end-to-end.
// Weights are wave-uniform in LDS; h/x live in a wave-private slab region.
// NO inter-wave dataflow inside the time loops -> barriers only around staging.
__global__ __launch_bounds__(1024, 4)
void vanilla_lstm(const float* __restrict__ obs,
                  const float* __restrict__ W_emb, const float* __restrict__ b_emb,
                  const float* __restrict__ Wih_e, const float* __restrict__ Whh_e,
                  const float* __restrict__ bih_e, const float* __restrict__ bhh_e,
                  const float* __restrict__ Wih_d, const float* __restrict__ Whh_d,
                  const float* __restrict__ bih_d, const float* __restrict__ bhh_d,
                  const float* __restrict__ W_fc,  const float* __restrict__ b_fc,
                  float* __restrict__ out)
{
    extern __shared__ __align__(16) char lds[];
    bf16x8* wlds  = (bf16x8*)(lds + OFF_W);
    __bf16* slab  = (__bf16*)(lds + OFF_SLAB);
    float4* embc  = (float4*)(lds + OFF_EMBC);
    float*  biasE = (float*) (lds + OFF_BIASE);
    float*  biasD = (float*) (lds + OFF_BIASD);
    float*  wfc   = (float*) (lds + OFF_WFC);
    float*  bfc   = (float*) (lds + OFF_BFC);

    const int tid  = threadIdx.x;
    const int bid  = blockIdx.x;
    const int lane = tid & 63;
    const int wid  = tid >> 6;              // 0..15
    const int m    = lane & 15;
    const int q    = lane >> 4;
    const int srow = wid * 16 + m;          // this lane's slab row (B-frag / emb row)
    const size_t gRowW = (size_t)bid * RPB + wid * 16;

    // A-frag staging: identical semantics to verified fill_wkt3 (lane(m,q) holds
    // W[n = c*64 + ug*16 + m][k = kt*32 + q*8 .. +7], prescaled), for ALL frags.
    auto stage_W = [&](const float* Wih, const float* Whh) {
        #pragma unroll
        for (int i = 0; i < 4; ++i) {
            const int e  = tid + i * 1024;      // 0..4095
            const int ln = e & 63;
            const int f  = e >> 6;              // (c*4+ug)*4+kt
            const int kt = f & 3, ug = (f >> 2) & 3, c = f >> 4;
            const float sc = (c == 2) ? SG : SIO;
            const int n  = c * 64 + ug * 16 + (ln & 15);
            const int kq = (ln >> 4) * 8;
            const float* s = (kt < 2) ? (Wih + n * 64 + kt * 32 + kq)
                                      : (Whh + n * 64 + (kt - 2) * 32 + kq);
            float4 a = *(const float4*)s;
            float4 b = *(const float4*)(s + 4);
            bf16x8 v;
            v[0] = (__bf16)(sc * a.x); v[1] = (__bf16)(sc * a.y);
            v[2] = (__bf16)(sc * a.z); v[3] = (__bf16)(sc * a.w);
            v[4] = (__bf16)(sc * b.x); v[5] = (__bf16)(sc * b.y);
            v[6] = (__bf16)(sc * b.z); v[7] = (__bf16)(sc * b.w);
            wlds[f * 64 + ln] = v;
        }
    };

    // ---- one-time staging ----
    stage_W(Wih_e, Whh_e);
    if (tid < 256) {
        const int ug_ = tid >> 6, c_ = (tid >> 4) & 3, u_ = tid & 15;
        const int g = c_ * 64 + ug_ * 16 + u_;
        const float sc = (c_ == 2) ? SG : SIO;
        biasE[tid] = sc * (bih_e[g] + bhh_e[g]);
        biasD[tid] = sc * (bih_d[g] + bhh_d[g]);
    }
    if (tid < 64)  embc[tid] = make_float4(W_emb[2 * tid], W_emb[2 * tid + 1], b_emb[tid], 0.f);
    if (tid < 128) wfc[tid]  = W_fc[tid];
    if (tid < 2)   bfc[tid]  = b_fc[tid];
    {   // zero h region (cols 64..127) of all 256 rows: 2048 uint4, 2/thread
        uint4 z; z.x = z.y = z.z = z.w = 0u;
        #pragma unroll
        for (int i = 0; i < 2; ++i) {
            const int idx = tid + i * 1024;
            const int r = idx >> 3, o = idx & 7;
            *(uint4*)&slab[r * SLST + 64 + o * 8] = z;
        }
    }
    __syncthreads();    // barrier #1: staging visible

    f32x4 cst[4];       // cell state: lane(m,q) reg r of cst[ug] = c[row srow][unit ug*16+q*4+r]
    #pragma unroll
    for (int i = 0; i < 4; ++i) cst[i] = f32x4{0.f, 0.f, 0.f, 0.f};

    // x staging for own rows: lane(m,q) covers row srow, cols q*16..q*16+15
    auto emb_write = [&](float px0, float px1) {
        bf16x8 v0, v1;
        #pragma unroll
        for (int j = 0; j < 8; ++j) {
            float4 wc = embc[q * 16 + j];
            v0[j] = (__bf16)fmaxf(fmaf(px0, wc.x, fmaf(px1, wc.y, wc.z)), 0.f);
        }
        #pragma unroll
        for (int j = 0; j < 8; ++j) {
            float4 wc = embc[q * 16 + 8 + j];
            v1[j] = (__bf16)fmaxf(fmaf(px0, wc.x, fmaf(px1, wc.y, wc.z)), 0.f);
        }
        *(bf16x8*)&slab[srow * SLST + q * 16]     = v0;
        *(bf16x8*)&slab[srow * SLST + q * 16 + 8] = v1;
    };

    // one LSTM step for this wave's 16 rows: gates (MFMA, weights from LDS,
    // B = own slab rows) then merged-denominator update, h -> own slab rows.
    auto step = [&](const float* biasp) {
        bf16x8 B0 = *(const bf16x8*)&slab[srow * SLST +  0 + q * 8];
        bf16x8 B1 = *(const bf16x8*)&slab[srow * SLST + 32 + q * 8];
        bf16x8 B2 = *(const bf16x8*)&slab[srow * SLST + 64 + q * 8];
        bf16x8 B3 = *(const bf16x8*)&slab[srow * SLST + 96 + q * 8];
        #pragma unroll
        for (int ug = 0; ug < 4; ++ug) {
            f32x4 acc[4];   // static indices after unroll (rule #20)
            #pragma unroll
            for (int c = 0; c < 4; ++c)
                acc[c] = *(const f32x4*)&biasp[(ug * 4 + c) * 16 + q * 4];
            #pragma unroll
            for (int c = 0; c < 4; ++c) {
                acc[c] = __builtin_amdgcn_mfma_f32_16x16x32_bf16(wlds[((c * 4 + ug) * 4 + 0) * 64 + lane], B0, acc[c], 0, 0, 0);
                acc[c] = __builtin_amdgcn_mfma_f32_16x16x32_bf16(wlds[((c * 4 + ug) * 4 + 1) * 64 + lane], B1, acc[c], 0, 0, 0);
                acc[c] = __builtin_amdgcn_mfma_f32_16x16x32_bf16(wlds[((c * 4 + ug) * 4 + 2) * 64 + lane], B2, acc[c], 0, 0, 0);
                acc[c] = __builtin_amdgcn_mfma_f32_16x16x32_bf16(wlds[((c * 4 + ug) * 4 + 3) * 64 + lane], B3, acc[c], 0, 0, 0);
            }
            f32x4 ci = cst[ug];
            bf16x4 h4;
            #pragma unroll
            for (int r = 0; r < 4; ++r) {
                const float Ef = exp2_(acc[1][r]);           // exp(-f)
                const float Ei = exp2_(acc[0][r]);           // exp(-i)
                const float Eg = exp2_(acc[2][r]);           // exp(2g)
                const float pf = 1.0f + Ef;
                const float t1 = (1.0f + Ei) * (1.0f + Eg);
                const float R  = rcp_(pf * t1);
                const float cN = fmaf(ci[r], t1, (Eg - 1.0f) * pf) * R;
                const float Eo = exp2_(acc[3][r]);           // exp(-o)
                const float Ec = exp2_(cN * SG);             // exp(2c)
                const float d2 = 1.0f + Eo;
                const float r2 = rcp_(fmaf(d2, Ec, d2));
                ci[r] = cN;
                h4[r] = (__bf16)((Ec - 1.0f) * r2);          // sig(o)*tanh(cN)
            }
            cst[ug] = ci;
            *(bf16x4*)&slab[srow * SLST + 64 + ug * 16 + q * 4] = h4;
        }
    };

    // ================= encoder (barrier-free) =================
    {
        f32x2 ov = *(const f32x2*)(obs + (gRowW + m) * (OBS * 2));
        emb_write(ov[0], ov[1]);                 // x(0) — same-wave write->read
    }
    for (int t = 0; t < OBS; ++t) {
        f32x2 ov;
        if (t + 1 < OBS) ov = *(const f32x2*)(obs + (gRowW + m) * (OBS * 2) + (t + 1) * 2);
        step(biasE);                             // reads x(t),h(t-1); writes h(t)
        if (t + 1 < OBS) emb_write(ov[0], ov[1]);// x(t+1) (after step consumed x(t))
    }

    // ================= decoder =================
    __syncthreads();                 // barrier #2: all waves done reading W_e
    stage_W(Wih_d, Whh_d);
    __syncthreads();                 // barrier #3: W_d visible

    const float bfc0 = bfc[0], bfc1 = bfc[1];
    const int rr = lane >> 2, seg = lane & 3;    // pred: 4 lanes per row

    for (int td = 0; td < PRED; ++td) {
        step(biasD);                             // h(td) for own rows

        // pred = h @ W_fc.T + b_fc for own 16 rows (same math as verified pred_phase)
        bf16x8 h0 = *(const bf16x8*)&slab[(wid * 16 + rr) * SLST + 64 + seg * 16];
        bf16x8 h1 = *(const bf16x8*)&slab[(wid * 16 + rr) * SLST + 64 + seg * 16 + 8];
        f32x4 w0 = *(const f32x4*)&wfc[seg * 16];
        f32x4 w1 = *(const f32x4*)&wfc[seg * 16 + 4];
        f32x4 w2 = *(const f32x4*)&wfc[seg * 16 + 8];
        f32x4 w3 = *(const f32x4*)&wfc[seg * 16 + 12];
        float p0 = (float)h0[0] * w0[0] + (float)h0[1] * w0[1] + (float)h0[2] * w0[2] + (float)h0[3] * w0[3]
                 + (float)h0[4] * w1[0] + (float)h0[5] * w1[1] + (float)h0[6] * w1[2] + (float)h0[7] * w1[3]
                 + (float)h1[0] * w2[0] + (float)h1[1] * w2[1] + (float)h1[2] * w2[2] + (float)h1[3] * w2[3]
                 + (float)h1[4] * w3[0] + (float)h1[5] * w3[1] + (float)h1[6] * w3[2] + (float)h1[7] * w3[3];
        f32x4 u0 = *(const f32x4*)&wfc[64 + seg * 16];
        f32x4 u1 = *(const f32x4*)&wfc[64 + seg * 16 + 4];
        f32x4 u2 = *(const f32x4*)&wfc[64 + seg * 16 + 8];
        f32x4 u3 = *(const f32x4*)&wfc[64 + seg * 16 + 12];
        float p1 = (float)h0[0] * u0[0] + (float)h0[1] * u0[1] + (float)h0[2] * u0[2] + (float)h0[3] * u0[3]
                 + (float)h0[4] * u1[0] + (float)h0[5] * u1[1] + (float)h0[6] * u1[2] + (float)h0[7] * u1[3]
                 + (float)h1[0] * u2[0] + (float)h1[1] * u2[1] + (float)h1[2] * u2[2] + (float)h1[3] * u2[3]
                 + (float)h1[4] * u3[0] + (float)h1[5] * u3[1] + (float)h1[6] * u3[2] + (float)h1[7] * u3[3];
        p0 += __shfl_xor(p0, 1, 64);  p0 += __shfl_xor(p0, 2, 64);   // sum over seg
        p1 += __shfl_xor(p1, 1, 64);  p1 += __shfl_xor(p1, 2, 64);
        p0 += bfc0;  p1 += bfc1;
        if (seg == 0)
            *(f32x2*)&out[((gRowW + rr) * PRED + td) * 2] = f32x2{p0, p1};

        if (td + 1 < PRED) {
            // redistribute: lane(m,q) needs pred of row srow = wid*16+m,
            // held by wave-lane m*4 (rr == m there). Intra-wave, deterministic.
            float px0 = __shfl(p0, m * 4, 64);
            float px1 = __shfl(p1, m * 4, 64);
            emb_write(px0, px1);                 // x(td+1) = relu(emb(pred))
        }
    }
}

extern "C" void kernel_launch(void* const* d_in, const int* in_sizes, int n_in,
                              void* d_out, int out_size, void* d_ws, size_t ws_size,
                              hipStream_t stream) {
    (void)in_sizes; (void)n_in; (void)d_ws; (void)ws_size; (void)out_size;
    const float* obs   = (const float*)d_in[0];
    const float* W_emb = (const float*)d_in[1];
    const float* b_emb = (const float*)d_in[2];
    const float* Wih_e = (const float*)d_in[3];
    const float* Whh_e = (const float*)d_in[4];
    const float* bih_e = (const float*)d_in[5];
    const float* bhh_e = (const float*)d_in[6];
    const float* Wih_d = (const float*)d_in[7];
    const float* Whh_d = (const float*)d_in[8];
    const float* bih_d = (const float*)d_in[9];
    const float* bhh_d = (const float*)d_in[10];
    const float* W_fc  = (const float*)d_in[11];
    const float* b_fc  = (const float*)d_in[12];
    float* o = (float*)d_out;

    static bool attr_set = false;
    if (!attr_set) {
        hipFuncSetAttribute((const void*)vanilla_lstm,
                            hipFuncAttributeMaxDynamicSharedMemorySize, LDS_BYTES);
        attr_set = true;
    }

    dim3 grid(GRID), block(1024);
    hipLaunchKernelGGL(vanilla_lstm, grid, block, LDS_BYTES, stream,
                       obs, W_emb, b_emb, Wih_e, Whh_e, bih_e, bhh_e,
                       Wih_d, Whh_d, bih_d, bhh_d, W_fc, b_fc, o);
}